// Round 5
// baseline (160.229 us; speedup 1.0000x reference)
//
#include <hip/hip_runtime.h>

#define HWOUT 50176   // 224*224
#define NBLK  1024    // stage1 grid size == rows of partial[]
#define CHUNK 256     // rows staged per block iteration
#define REPS  8       // instrumentation: repeat whole body; final rep == 1x result

typedef __attribute__((ext_vector_type(8))) short short8;
typedef __attribute__((ext_vector_type(4))) float f32x4;

__device__ __forceinline__ float fast_sigmoid(float x) {
    float t = __builtin_amdgcn_exp2f(-1.44269504088896340736f * x);
    return __builtin_amdgcn_rcpf(1.0f + t);
}
__device__ __forceinline__ float silu_f(float x) { return x * fast_sigmoid(x); }

__device__ __forceinline__ short to_bf16_bits(float f) {
    unsigned u = __builtin_bit_cast(unsigned, f);
    u += 0x7FFFu + ((u >> 16) & 1u);   // round-to-nearest-even
    return (short)(u >> 16);
}

// ---------------- Stage 1 (R2 structure + reps loop)
__global__ __launch_bounds__(256) void k_stage1(const float* __restrict__ x,
                                                const float* __restrict__ W1,
                                                const float* __restrict__ b1,
                                                float* __restrict__ partial,
                                                int N, int reps) {
    __shared__ short xs[CHUNK * 8];     // bf16 rows, 8-padded (16B each)
    __shared__ float red[4][64];
    const int t = threadIdx.x;
    const int lane = t & 63;
    const int wave = t >> 6;

    // B fragments: bf[g][j] = W1pad[8*(lane>>4)+j][g*16+(lane&15)], k>=7 -> 0
    const int krow = (lane >> 4) * 8;
    const int c = lane & 15;
    short8 bf[4];
    float bcol[4];
#pragma unroll
    for (int g = 0; g < 4; ++g) {
#pragma unroll
        for (int j = 0; j < 8; ++j) {
            int k = krow + j;
            float v = (k < 7) ? W1[k * 64 + g * 16 + c] : 0.0f;
            bf[g][j] = to_bf16_bits(v);
        }
        bcol[g] = b1[g * 16 + c];
    }

    const int nchunk = (N + CHUNK - 1) / CHUNK;
    const short8 zero8 = {0, 0, 0, 0, 0, 0, 0, 0};
    const f32x4 zero4 = {0.0f, 0.0f, 0.0f, 0.0f};

    for (int rep = 0; rep < reps; ++rep) {
        asm volatile("" ::: "memory");   // block cross-rep hoisting
        float accf[4] = {0.0f, 0.0f, 0.0f, 0.0f};

        for (int ch = blockIdx.x; ch < nchunk; ch += NBLK) {
            const int row = ch * CHUNK + t;
            __syncthreads();              // prior tile/epilogue reads done
            {
                float v[7];
                if (row < N) {
#pragma unroll
                    for (int k = 0; k < 7; ++k) v[k] = x[row * 7 + k];
                } else {
#pragma unroll
                    for (int k = 0; k < 7; ++k) v[k] = 0.0f;
                }
                short8 p;
#pragma unroll
                for (int k = 0; k < 7; ++k) p[k] = to_bf16_bits(silu_f(v[k]));
                p[7] = 0;
                *reinterpret_cast<short8*>(&xs[t * 8]) = p;
            }
            __syncthreads();

            const bool full = (ch * CHUNK + CHUNK <= N);
            const int chbase = ch * CHUNK;
#pragma unroll
            for (int tt = 0; tt < 4; ++tt) {
                const int tile = wave * 4 + tt;
                short8 av = *reinterpret_cast<short8*>(&xs[(tile * 16 + c) * 8]);
                av = (lane < 16) ? av : zero8;   // lanes>=16 are K-pad
#pragma unroll
                for (int g = 0; g < 4; ++g) {
                    f32x4 d = __builtin_amdgcn_mfma_f32_16x16x32_bf16(av, bf[g], zero4, 0, 0, 0);
                    if (full) {
#pragma unroll
                        for (int r = 0; r < 4; ++r) accf[g] += silu_f(d[r] + bcol[g]);
                    } else {
                        const int r0 = chbase + tile * 16 + (lane >> 4) * 4;
#pragma unroll
                        for (int r = 0; r < 4; ++r) {
                            float s = silu_f(d[r] + bcol[g]);
                            accf[g] += (r0 + r < N) ? s : 0.0f;
                        }
                    }
                }
            }
        }

        // epilogue: collapse rows, cross-wave reduce, store (observable each rep)
#pragma unroll
        for (int g = 0; g < 4; ++g) {
            accf[g] += __shfl_xor(accf[g], 16, 64);
            accf[g] += __shfl_xor(accf[g], 32, 64);
        }
        __syncthreads();                 // red[] safe to overwrite
        if (lane < 16) {
#pragma unroll
            for (int g = 0; g < 4; ++g) red[wave][g * 16 + lane] = accf[g];
        }
        __syncthreads();
        if (t < 64)
            partial[blockIdx.x * 64 + t] = red[0][t] + red[1][t] + red[2][t] + red[3][t];
    }
}

// ---------------- Stage 2 (R2 structure + reps loop)
__global__ __launch_bounds__(256) void k_out2(const float* __restrict__ partial,
                                              const float* __restrict__ W2,
                                              const float* __restrict__ b2,
                                              float* __restrict__ out,
                                              float invN, int reps) {
    __shared__ float4 red[256];
    __shared__ float ml[64];
    const int t = threadIdx.x;
    const int c4 = t & 15;
    const int grp = t >> 4;
    const float4* p4 = reinterpret_cast<const float4*>(partial);

    for (int rep = 0; rep < reps; ++rep) {
        asm volatile("" ::: "memory");   // block cross-rep hoisting

        float4 s = {0.0f, 0.0f, 0.0f, 0.0f};
#pragma unroll 8
        for (int r = grp; r < NBLK; r += 16) {
            float4 v = p4[r * 16 + c4];
            s.x += v.x; s.y += v.y; s.z += v.z; s.w += v.w;
        }
        red[t] = s;
        __syncthreads();
        if (t < 16) {
            float4 a = {0.0f, 0.0f, 0.0f, 0.0f};
#pragma unroll
            for (int g = 0; g < 16; ++g) {
                float4 v = red[g * 16 + t];
                a.x += v.x; a.y += v.y; a.z += v.z; a.w += v.w;
            }
            ml[4 * t + 0] = a.x * invN;
            ml[4 * t + 1] = a.y * invN;
            ml[4 * t + 2] = a.z * invN;
            ml[4 * t + 3] = a.w * invN;
        }
        __syncthreads();

        const int j = blockIdx.x * 256 + t;
        float acc = b2[j];
#pragma unroll
        for (int k4 = 0; k4 < 16; ++k4) {
            float4 mv = *reinterpret_cast<float4*>(&ml[k4 * 4]);
            acc = fmaf(mv.x, W2[(size_t)(k4 * 4 + 0) * HWOUT + j], acc);
            acc = fmaf(mv.y, W2[(size_t)(k4 * 4 + 1) * HWOUT + j], acc);
            acc = fmaf(mv.z, W2[(size_t)(k4 * 4 + 2) * HWOUT + j], acc);
            acc = fmaf(mv.w, W2[(size_t)(k4 * 4 + 3) * HWOUT + j], acc);
        }
        float e = silu_f(acc);
        out[j] = fminf(fmaxf(e, 0.0f), 1.0f);
        __syncthreads();                 // red[]/ml[] reuse safe next rep
    }
}

extern "C" void kernel_launch(void* const* d_in, const int* in_sizes, int n_in,
                              void* d_out, int out_size, void* d_ws, size_t ws_size,
                              hipStream_t stream) {
    const float* x  = (const float*)d_in[0];
    const float* W1 = (const float*)d_in[1];
    const float* b1 = (const float*)d_in[2];
    const float* W2 = (const float*)d_in[3];
    const float* b2 = (const float*)d_in[4];
    float* out = (float*)d_out;

    const int N = in_sizes[0] / 7;
    float* partial = (float*)d_ws;   // NBLK*64 floats

    k_stage1<<<NBLK, 256, 0, stream>>>(x, W1, b1, partial, N, REPS);
    k_out2<<<HWOUT / 256, 256, 0, stream>>>(partial, W2, b2, out, 1.0f / (float)N, REPS);
}

// Round 6
// 23.563 us; speedup vs baseline: 6.8001x; 6.8001x over previous
//
#include <hip/hip_runtime.h>

#define HWOUT 50176   // 224*224
#define NBLK  256     // stage1 grid; partial[] rows
#define CHUNK 1024    // rows per block-iteration (1024 threads, 1 row/thread)
#define NWAVE 16

typedef __attribute__((ext_vector_type(8))) short short8;
typedef __attribute__((ext_vector_type(4))) float f32x4;

__device__ __forceinline__ float fast_sigmoid(float x) {
    float t = __builtin_amdgcn_exp2f(-1.44269504088896340736f * x);
    return __builtin_amdgcn_rcpf(1.0f + t);
}
__device__ __forceinline__ float silu_f(float x) { return x * fast_sigmoid(x); }

__device__ __forceinline__ short to_bf16_bits(float f) {
    unsigned u = __builtin_bit_cast(unsigned, f);
    u += 0x7FFFu + ((u >> 16) & 1u);   // round-to-nearest-even
    return (short)(u >> 16);
}

// ---------------- Stage 1: partial[b][c] = sum over block's rows of
//   silu( silu(x_row) . W1[:,c] + b1[c] )
// MFMA 16x16x32 bf16; bias via C operand; phantom rows corrected analytically.
__global__ __launch_bounds__(1024) void k_stage1(const float* __restrict__ x,
                                                 const float* __restrict__ W1,
                                                 const float* __restrict__ b1,
                                                 float* __restrict__ partial,
                                                 int N) {
    __shared__ short xs[CHUNK * 8];     // 16 KB bf16 rows (7 padded to 8)
    __shared__ float red[NWAVE][64];    // 4 KB
    const int t = threadIdx.x;
    const int lane = t & 63;
    const int wave = t >> 6;

    // B fragments: bf[g][j] = W1pad[8*(lane>>4)+j][g*16+(lane&15)], k>=7 -> 0
    const int krow = (lane >> 4) * 8;
    const int c = lane & 15;
    short8 bf[4];
    f32x4 biasC[4];
#pragma unroll
    for (int g = 0; g < 4; ++g) {
#pragma unroll
        for (int j = 0; j < 8; ++j) {
            int k = krow + j;
            float v = (k < 7) ? W1[k * 64 + g * 16 + c] : 0.0f;
            bf[g][j] = to_bf16_bits(v);
        }
        float bb = b1[g * 16 + c];
        biasC[g] = (f32x4){bb, bb, bb, bb};
    }

    f32x4 accv[4];
#pragma unroll
    for (int g = 0; g < 4; ++g) accv[g] = (f32x4){0.0f, 0.0f, 0.0f, 0.0f};

    const int nchunk = (N + CHUNK - 1) / CHUNK;
    const short8 zero8 = {0, 0, 0, 0, 0, 0, 0, 0};
    const f32x4 onev = {1.0f, 1.0f, 1.0f, 1.0f};
    const f32x4 nlog2e = {-1.44269504088896f, -1.44269504088896f,
                          -1.44269504088896f, -1.44269504088896f};

    bool did_last = false;               // this block processed the final chunk
    for (int ch = blockIdx.x; ch < nchunk; ch += NBLK) {
        did_last |= (ch == nchunk - 1);
        const int row = ch * CHUNK + t;
        __syncthreads();                 // prior tile reads done before overwrite
        {
            float v[7];
            if (row < N) {
#pragma unroll
                for (int k = 0; k < 7; ++k) v[k] = x[(size_t)row * 7 + k];
            } else {
#pragma unroll
                for (int k = 0; k < 7; ++k) v[k] = 0.0f;   // phantom row -> A=0
            }
            short8 p;
#pragma unroll
            for (int k = 0; k < 7; ++k) p[k] = to_bf16_bits(silu_f(v[k]));
            p[7] = 0;
            *reinterpret_cast<short8*>(&xs[t * 8]) = p;
        }
        __syncthreads();

#pragma unroll
        for (int tt = 0; tt < 4; ++tt) {
            const int tile = wave * 4 + tt;
            short8 av = *reinterpret_cast<short8*>(&xs[(tile * 16 + c) * 8]);
            av = (lane < 16) ? av : zero8;      // lanes>=16 are K-pad
#pragma unroll
            for (int g = 0; g < 4; ++g) {
                f32x4 d = __builtin_amdgcn_mfma_f32_16x16x32_bf16(av, bf[g], biasC[g], 0, 0, 0);
                // vector silu: d * rcp(1 + exp2(-log2e*d)), packed-math friendly
                f32x4 targ = d * nlog2e;
                f32x4 ex;
                ex[0] = __builtin_amdgcn_exp2f(targ[0]);
                ex[1] = __builtin_amdgcn_exp2f(targ[1]);
                ex[2] = __builtin_amdgcn_exp2f(targ[2]);
                ex[3] = __builtin_amdgcn_exp2f(targ[3]);
                f32x4 den = ex + onev;
                f32x4 r;
                r[0] = __builtin_amdgcn_rcpf(den[0]);
                r[1] = __builtin_amdgcn_rcpf(den[1]);
                r[2] = __builtin_amdgcn_rcpf(den[2]);
                r[3] = __builtin_amdgcn_rcpf(den[3]);
                accv[g] = d * r + accv[g];      // packed fma
            }
        }
    }

    // collapse vector acc -> scalar per (g, col); rows split across lane>>4
    float accf[4];
#pragma unroll
    for (int g = 0; g < 4; ++g) {
        accf[g] = (accv[g][0] + accv[g][1]) + (accv[g][2] + accv[g][3]);
        accf[g] += __shfl_xor(accf[g], 16, 64);
        accf[g] += __shfl_xor(accf[g], 32, 64);
    }
    __syncthreads();
    if (lane < 16) {
#pragma unroll
        for (int g = 0; g < 4; ++g) red[wave][g * 16 + lane] = accf[g];
    }
    __syncthreads();
    if (t < 64) {
        float s = 0.0f;
#pragma unroll
        for (int wv = 0; wv < NWAVE; ++wv) s += red[wv][t];
        if (did_last) {
            // phantom rows contributed silu(b1[c]) each; remove exactly
            const int phantom = nchunk * CHUNK - N;
            s -= (float)phantom * silu_f(b1[t]);
        }
        partial[blockIdx.x * 64 + t] = s;
    }
}

// ---------------- Stage 2: redundant small reduce (64KB) + W2 matvec.
__global__ __launch_bounds__(256) void k_out2(const float* __restrict__ partial,
                                              const float* __restrict__ W2,
                                              const float* __restrict__ b2,
                                              float* __restrict__ out,
                                              float invN) {
    __shared__ float4 red[256];
    __shared__ float ml[64];
    const int t = threadIdx.x;
    const int c4 = t & 15;     // float4 column group
    const int grp = t >> 4;    // 0..15
    const float4* p4 = reinterpret_cast<const float4*>(partial);

    float4 s = {0.0f, 0.0f, 0.0f, 0.0f};
#pragma unroll
    for (int r = grp; r < NBLK; r += 16) {   // 16 coalesced float4 loads
        float4 v = p4[r * 16 + c4];
        s.x += v.x; s.y += v.y; s.z += v.z; s.w += v.w;
    }
    red[t] = s;
    __syncthreads();
    if (t < 16) {
        float4 a = {0.0f, 0.0f, 0.0f, 0.0f};
#pragma unroll
        for (int g = 0; g < 16; ++g) {
            float4 v = red[g * 16 + t];
            a.x += v.x; a.y += v.y; a.z += v.z; a.w += v.w;
        }
        ml[4 * t + 0] = a.x * invN;
        ml[4 * t + 1] = a.y * invN;
        ml[4 * t + 2] = a.z * invN;
        ml[4 * t + 3] = a.w * invN;
    }
    __syncthreads();

    const int j = blockIdx.x * 256 + t;   // grid == HWOUT/256
    float acc[8];
#pragma unroll
    for (int i = 0; i < 8; ++i) acc[i] = 0.0f;
#pragma unroll
    for (int k8 = 0; k8 < 8; ++k8) {
#pragma unroll
        for (int i = 0; i < 8; ++i) {
            const int k = k8 * 8 + i;
            acc[i] = fmaf(ml[k], W2[(size_t)k * HWOUT + j], acc[i]);
        }
    }
    float a01 = acc[0] + acc[1], a23 = acc[2] + acc[3];
    float a45 = acc[4] + acc[5], a67 = acc[6] + acc[7];
    float e = ((a01 + a23) + (a45 + a67)) + b2[j];
    e = silu_f(e);
    out[j] = fminf(fmaxf(e, 0.0f), 1.0f);
}

extern "C" void kernel_launch(void* const* d_in, const int* in_sizes, int n_in,
                              void* d_out, int out_size, void* d_ws, size_t ws_size,
                              hipStream_t stream) {
    const float* x  = (const float*)d_in[0];
    const float* W1 = (const float*)d_in[1];
    const float* b1 = (const float*)d_in[2];
    const float* W2 = (const float*)d_in[3];
    const float* b2 = (const float*)d_in[4];
    float* out = (float*)d_out;

    const int N = in_sizes[0] / 7;
    float* partial = (float*)d_ws;   // NBLK*64 floats = 64 KB

    k_stage1<<<NBLK, 1024, 0, stream>>>(x, W1, b1, partial, N);
    k_out2<<<HWOUT / 256, 256, 0, stream>>>(partial, W2, b2, out, 1.0f / (float)N);
}